// Round 1
// baseline (17066.324 us; speedup 1.0000x reference)
//
#include <hip/hip_runtime.h>
#include <hip/hip_bf16.h>

// RNN_73418170958322 on MI355X
// out[t] = (h_{t+1}) @ Wo^T + bo,  h_{t+1} = tanh(EW[x[t]] + h_t @ Wh^T + bh),
// EW = emb @ Wi^T + bi (V=512 rows only -> precompute instead of 275 GFLOP einsum).
//
// Persistent kernel: 256 blocks x 256 thr. Block(g=blk&7,c=blk>>3): batches [16g,16g+16),
// h-cols [64c,64c+64), o-cols [16c,16c+16). Wh B-frags held in VGPRs (256/wave).
// Per-step h exchange via global bf16 ping-pong buffer + per-group (32 blocks) monotonic
// counter barrier with agent-scope release add / relaxed spin + acquire fence.
// LDS (exactly 64KB): staged h_t as [k-chunk][row][16B] (bank-balanced for ds_read_b128
// A-frags); aliased as o-reduction buffer after the post-MFMA barrier.

#define T_DIM 1024
#define B_DIM 128
#define V_DIM 512
#define H_DIM 2048
#define O_DIM 512

typedef __attribute__((ext_vector_type(4))) float f32x4;
typedef __attribute__((ext_vector_type(8))) short s16x8;

// workspace layout (bytes)
#define WS_WHB   0u          // bf16 Wh      [2048,2048]  8 MB
#define WS_WOB   8388608u    // bf16 Wo      [512,2048]   2 MB
#define WS_EMBB  10485760u   // bf16 emb     [512,512]    512 KB
#define WS_WIB   11010048u   // bf16 Wi      [2048,512]   2 MB
#define WS_EW    13107200u   // f32  EW      [512,2048]   4 MB
#define WS_HBUF  17301504u   // bf16 h ping-pong [2][128,2048] 1 MB
#define WS_BAR   18350080u   // int  barrier counters, 8 groups x 128B

__device__ __forceinline__ float tanh_fast(float v) {
  v = fminf(15.0f, fmaxf(-15.0f, v));
  float e = __expf(2.0f * v);
  return (e - 1.0f) / (e + 1.0f);
}

__global__ __launch_bounds__(256) void cast_bf16_kernel(const float* __restrict__ src,
                                                        __hip_bfloat16* __restrict__ dst,
                                                        int n8) {
  int idx = blockIdx.x * 256 + threadIdx.x;
  if (idx >= n8) return;
  const f32x4* s4 = (const f32x4*)src;
  f32x4 a = s4[idx * 2], b = s4[idx * 2 + 1];
  short o[8];
#pragma unroll
  for (int j = 0; j < 4; ++j) {
    __hip_bfloat16 t1 = __float2bfloat16(a[j]);
    __hip_bfloat16 t2 = __float2bfloat16(b[j]);
    o[j] = __builtin_bit_cast(short, t1);
    o[j + 4] = __builtin_bit_cast(short, t2);
  }
  s16x8 v = {o[0], o[1], o[2], o[3], o[4], o[5], o[6], o[7]};
  ((s16x8*)dst)[idx] = v;
}

// EW[v,j] = sum_u emb[v,u]*Wi[j,u] + bi[j].  One 16x16 tile per wave. M=512,N=2048,K=512.
__global__ __launch_bounds__(256) void ew_kernel(const __hip_bfloat16* __restrict__ embb,
                                                 const __hip_bfloat16* __restrict__ Wib,
                                                 const float* __restrict__ bi,
                                                 float* __restrict__ EW) {
  int wid = blockIdx.x * 4 + (threadIdx.x >> 6);
  int lane = threadIdx.x & 63;
  int mt = wid >> 7;    // 0..31
  int nt = wid & 127;   // 0..127
  int m16 = lane & 15, q = lane >> 4;
  const s16x8* arow = (const s16x8*)(embb + (size_t)(mt * 16 + m16) * V_DIM + q * 8);
  const s16x8* brow = (const s16x8*)(Wib + (size_t)(nt * 16 + m16) * V_DIM + q * 8);
  f32x4 acc = {0, 0, 0, 0};
#pragma unroll
  for (int kk = 0; kk < 16; ++kk) {
    s16x8 af = arow[kk * 4];
    s16x8 bf = brow[kk * 4];
    acc = __builtin_amdgcn_mfma_f32_16x16x32_bf16(af, bf, acc, 0, 0, 0);
  }
  float biv = bi[nt * 16 + m16];
#pragma unroll
  for (int ii = 0; ii < 4; ++ii)
    EW[(size_t)(mt * 16 + q * 4 + ii) * H_DIM + nt * 16 + m16] = acc[ii] + biv;
}

__global__ __launch_bounds__(256, 1) void rnn_persistent(
    const int* __restrict__ x, const float* __restrict__ EW,
    const __hip_bfloat16* __restrict__ Whb, const __hip_bfloat16* __restrict__ Wob,
    const float* __restrict__ bh, const float* __restrict__ bo,
    __hip_bfloat16* __restrict__ hbuf, int* __restrict__ bar, float* __restrict__ out) {
  extern __shared__ char smem[];
  float* o_red = (float*)smem;  // aliases A-stage; only touched after post-MFMA sync

  const int tid = threadIdx.x;
  const int lane = tid & 63;
  const int w = tid >> 6;            // wave 0..3
  const int g = blockIdx.x & 7;      // batch group (XCD-affine heuristic)
  const int c = blockIdx.x >> 3;     // col group 0..31
  const int b0 = g << 4;
  const int hcol0 = c << 6;
  const int ocol0 = c << 4;
  const int m16 = lane & 15;
  const int q = lane >> 4;

  // one-time: Wh B-fragments for this wave's 16 h-cols, all K=2048 -> 64 frags in VGPRs
  s16x8 bf_h[64];
  {
    const s16x8* wrow =
        (const s16x8*)(Whb + (size_t)(hcol0 + (w << 4) + m16) * H_DIM + q * 8);
#pragma unroll
    for (int kk = 0; kk < 64; ++kk) bf_h[kk] = wrow[kk * 4];
  }
  // one-time: Wo B-fragments for this wave's K-slice [512w, 512w+512)
  s16x8 bf_o[16];
  {
    const s16x8* orow =
        (const s16x8*)(Wob + (size_t)(ocol0 + m16) * H_DIM + (w << 9) + q * 8);
#pragma unroll
    for (int kk = 0; kk < 16; ++kk) bf_o[kk] = orow[kk * 4];
  }
  const float bh_v = bh[hcol0 + (w << 4) + m16];
  const float bo_v = bo[ocol0 + (tid & 15)];

  int* bar_g = bar + g * 32;  // 128B-padded counter per group

  const int sr = tid >> 4;  // staging row 0..15
  const int sc = tid & 15;  // staging chunk 0..15

  for (int i = 0; i <= T_DIM; ++i) {
    // wait until all 32 blocks of the group stored s_i (each adds once per step)
    if (i > 0 && tid == 0) {
      const int target = i << 5;
      while (__hip_atomic_load(bar_g, __ATOMIC_RELAXED, __HIP_MEMORY_SCOPE_AGENT) < target)
        __builtin_amdgcn_s_sleep(8);
      __builtin_amdgcn_fence(__ATOMIC_ACQUIRE, "agent");
    }
    __syncthreads();

    // stage s_i[b0..b0+16, :] -> LDS [chunk=k/8][row][16B]; coalesced global reads
    {
      const __hip_bfloat16* hsrc = hbuf + (size_t)(i & 1) * (B_DIM * H_DIM) +
                                   (size_t)(b0 + sr) * H_DIM;
#pragma unroll
      for (int it = 0; it < 16; ++it) {
        int ck = sc + (it << 4);
        s16x8 v = *(const s16x8*)(hsrc + (ck << 3));
        *(s16x8*)(smem + (ck << 8) + (sr << 4)) = v;
      }
    }
    __syncthreads();

    f32x4 acc[4], acco[2];
#pragma unroll
    for (int j = 0; j < 4; ++j) acc[j] = (f32x4){0, 0, 0, 0};
    acco[0] = (f32x4){0, 0, 0, 0};
    acco[1] = (f32x4){0, 0, 0, 0};

    const char* abase = smem + (q << 8) + (m16 << 4);
#pragma unroll
    for (int kk = 0; kk < 64; ++kk) {
      s16x8 af = *(const s16x8*)(abase + (kk << 10));
      acc[kk & 3] = __builtin_amdgcn_mfma_f32_16x16x32_bf16(af, bf_h[kk], acc[kk & 3], 0, 0, 0);
      int ko = kk - (w << 4);
      if ((unsigned)ko < 16u)  // this wave's o K-slice reuses the same A-frag
        acco[ko & 1] = __builtin_amdgcn_mfma_f32_16x16x32_bf16(af, bf_o[ko], acco[ko & 1], 0, 0, 0);
    }

    if (i < T_DIM) {  // h_{i+1} = tanh(EW[x_i] + acc + bh)
      f32x4 a = (acc[0] + acc[1]) + (acc[2] + acc[3]);
      const int n = hcol0 + (w << 4) + m16;
      __hip_bfloat16* hdst = hbuf + (size_t)((i + 1) & 1) * (B_DIM * H_DIM);
#pragma unroll
      for (int ii = 0; ii < 4; ++ii) {
        int m = (q << 2) + ii;
        int b = b0 + m;
        int xv = x[i * B_DIM + b];
        float pre = EW[(size_t)xv * H_DIM + n] + bh_v + a[ii];
        float th = tanh_fast(pre);
        hdst[(size_t)b * H_DIM + n] = __float2bfloat16(th);
        if (i == T_DIM - 1)  // final hidden state, f32, appended after out
          out[(size_t)T_DIM * B_DIM * O_DIM + (size_t)b * H_DIM + n] = th;
      }
    }

    __syncthreads();  // all A-frag LDS reads done -> o_red may alias

    if (i > 0) {
      f32x4 ao = acco[0] + acco[1];
#pragma unroll
      for (int ii = 0; ii < 4; ++ii)
        o_red[(w << 8) + ((q << 2) + ii) * 16 + m16] = ao[ii];
    }
    if (i < T_DIM && tid == 0) {  // signal: s_{i+1} stored (after the sync above)
      __hip_atomic_fetch_add(bar_g, 1, __ATOMIC_RELEASE, __HIP_MEMORY_SCOPE_AGENT);
    }
    __syncthreads();
    if (i > 0) {  // out[i-1] = sum of 4 wave partials + bo
      float v = o_red[tid] + o_red[256 + tid] + o_red[512 + tid] + o_red[768 + tid] + bo_v;
      int m = tid >> 4, n = tid & 15;
      out[(size_t)(i - 1) * (B_DIM * O_DIM) + (size_t)(b0 + m) * O_DIM + ocol0 + n] = v;
    }
  }
}

extern "C" void kernel_launch(void* const* d_in, const int* in_sizes, int n_in,
                              void* d_out, int out_size, void* d_ws, size_t ws_size,
                              hipStream_t stream) {
  const int* x = (const int*)d_in[0];
  const float* emb = (const float*)d_in[1];
  const float* Wi = (const float*)d_in[2];
  const float* bi = (const float*)d_in[3];
  const float* Wh = (const float*)d_in[4];
  const float* bh = (const float*)d_in[5];
  const float* Wo = (const float*)d_in[6];
  const float* bo = (const float*)d_in[7];
  float* out = (float*)d_out;
  char* ws = (char*)d_ws;

  __hip_bfloat16* Whb = (__hip_bfloat16*)(ws + WS_WHB);
  __hip_bfloat16* Wob = (__hip_bfloat16*)(ws + WS_WOB);
  __hip_bfloat16* embb = (__hip_bfloat16*)(ws + WS_EMBB);
  __hip_bfloat16* Wib = (__hip_bfloat16*)(ws + WS_WIB);
  float* EW = (float*)(ws + WS_EW);
  __hip_bfloat16* hbuf = (__hip_bfloat16*)(ws + WS_HBUF);
  int* bar = (int*)(ws + WS_BAR);

  // zero h ping-pong (s_0 = 0) and barrier counters
  hipMemsetAsync(ws + WS_HBUF, 0, (WS_BAR - WS_HBUF) + 1024, stream);

  cast_bf16_kernel<<<2048, 256, 0, stream>>>(Wh, Whb, 524288);
  cast_bf16_kernel<<<512, 256, 0, stream>>>(Wo, Wob, 131072);
  cast_bf16_kernel<<<128, 256, 0, stream>>>(emb, embb, 32768);
  cast_bf16_kernel<<<512, 256, 0, stream>>>(Wi, Wib, 131072);
  ew_kernel<<<1024, 256, 0, stream>>>(embb, Wib, bi, EW);
  rnn_persistent<<<256, 256, 65536, stream>>>(x, EW, Whb, Wob, bh, bo, hbuf, bar, out);
}

// Round 2
// 9386.602 us; speedup vs baseline: 1.8182x; 1.8182x over previous
//
#include <hip/hip_runtime.h>
#include <hip/hip_bf16.h>

// RNN_73418170958322 on MI355X
// out[t] = h_{t+1} @ Wo^T + bo,  h_{t+1} = tanh(EW[x[t]] + h_t @ Wh^T + bh),
// EW = emb @ Wi^T + bi  (V=512 rows -> precompute; kills the 275 GFLOP einsum).
//
// Persistent kernel: 256 blocks x 256 thr. Block(g=blk&7,c=blk>>3): batches [16g,16g+16),
// h-cols [64c,64c+64), o-cols [16c,16c+16). Wh B-frags in VGPRs (256/wave), Wo K-slice too.
// Cross-block h exchange via DEVICE-SCOPE RELAXED atomics only (sc-flagged ops served by
// the MALL/Infinity-Cache, which IS cross-XCD coherent) -> no buffer_wbl2 / buffer_inv
// cache walks in the loop (R1's 17us/step killer). Producer ordering: every thread drains
// vmcnt(0), block barrier, then one relaxed flag-add per block. hbuf is ONLY ever touched
// by device-scope ops so the MALL copy is always authoritative (step 0 synthesizes h=0).
// LDS staging uses XOR swizzle row'=row^(chunk&15): R1 had 16-way write conflicts
// (chunk stride 256B = 0 mod 32 banks); swizzle balances all banks for b64 writes and
// keeps b128 A-frag reads balanced.

#define T_DIM 1024
#define B_DIM 128
#define V_DIM 512
#define H_DIM 2048
#define O_DIM 512

typedef __attribute__((ext_vector_type(4))) float f32x4;
typedef __attribute__((ext_vector_type(8))) short s16x8;
typedef unsigned long long u64;

// workspace layout (bytes)
#define WS_WHB   0u          // bf16 Wh      [2048,2048]  8 MB
#define WS_WOB   8388608u    // bf16 Wo      [512,2048]   2 MB
#define WS_EMBB  10485760u   // bf16 emb     [512,512]    512 KB
#define WS_WIB   11010048u   // bf16 Wi      [2048,512]   2 MB
#define WS_EW    13107200u   // f32  EW      [512,2048]   4 MB
#define WS_HBUF  17301504u   // bf16 h ping-pong [2][128,2048] 1 MB (device-scope ops only)
#define WS_BAR   18350080u   // int  barrier counters, 8 groups x 128B

__device__ __forceinline__ float tanh_fast(float v) {
  v = fminf(15.0f, fmaxf(-15.0f, v));
  float e = __expf(2.0f * v);
  return (e - 1.0f) / (e + 1.0f);
}

__global__ __launch_bounds__(256) void cast_bf16_kernel(const float* __restrict__ src,
                                                        __hip_bfloat16* __restrict__ dst,
                                                        int n8) {
  int idx = blockIdx.x * 256 + threadIdx.x;
  if (idx >= n8) return;
  const f32x4* s4 = (const f32x4*)src;
  f32x4 a = s4[idx * 2], b = s4[idx * 2 + 1];
  short o[8];
#pragma unroll
  for (int j = 0; j < 4; ++j) {
    __hip_bfloat16 t1 = __float2bfloat16(a[j]);
    __hip_bfloat16 t2 = __float2bfloat16(b[j]);
    o[j] = __builtin_bit_cast(short, t1);
    o[j + 4] = __builtin_bit_cast(short, t2);
  }
  s16x8 v = {o[0], o[1], o[2], o[3], o[4], o[5], o[6], o[7]};
  ((s16x8*)dst)[idx] = v;
}

// EW[v,j] = sum_u emb[v,u]*Wi[j,u] + bi[j]. One 16x16 tile per wave. M=512,N=2048,K=512.
// Block 0 also initializes the barrier counters via device-scope atomic stores (so the
// MALL copy is authoritative before the persistent kernel's sc-flagged RMWs touch them).
__global__ __launch_bounds__(256) void ew_kernel(const __hip_bfloat16* __restrict__ embb,
                                                 const __hip_bfloat16* __restrict__ Wib,
                                                 const float* __restrict__ bi,
                                                 float* __restrict__ EW,
                                                 int* __restrict__ bar) {
  if (blockIdx.x == 0) {
    __hip_atomic_store(bar + threadIdx.x, 0, __ATOMIC_RELAXED, __HIP_MEMORY_SCOPE_AGENT);
  }
  int wid = blockIdx.x * 4 + (threadIdx.x >> 6);
  int lane = threadIdx.x & 63;
  int mt = wid >> 7;    // 0..31
  int nt = wid & 127;   // 0..127
  int m16 = lane & 15, q = lane >> 4;
  const s16x8* arow = (const s16x8*)(embb + (size_t)(mt * 16 + m16) * V_DIM + q * 8);
  const s16x8* brow = (const s16x8*)(Wib + (size_t)(nt * 16 + m16) * V_DIM + q * 8);
  f32x4 acc = {0, 0, 0, 0};
#pragma unroll
  for (int kk = 0; kk < 16; ++kk) {
    s16x8 af = arow[kk * 4];
    s16x8 bf = brow[kk * 4];
    acc = __builtin_amdgcn_mfma_f32_16x16x32_bf16(af, bf, acc, 0, 0, 0);
  }
  float biv = bi[nt * 16 + m16];
#pragma unroll
  for (int ii = 0; ii < 4; ++ii)
    EW[(size_t)(mt * 16 + q * 4 + ii) * H_DIM + nt * 16 + m16] = acc[ii] + biv;
}

__global__ __launch_bounds__(256, 1) void rnn_persistent(
    const int* __restrict__ x, const float* __restrict__ EW,
    const __hip_bfloat16* __restrict__ Whb, const __hip_bfloat16* __restrict__ Wob,
    const float* __restrict__ bh, const float* __restrict__ bo,
    unsigned short* __restrict__ hbuf, int* __restrict__ bar, float* __restrict__ out) {
  extern __shared__ char smem[];
  float* o_red = (float*)smem;  // aliases A-stage; only touched after post-MFMA sync

  const int tid = threadIdx.x;
  const int lane = tid & 63;
  const int w = tid >> 6;            // wave 0..3
  const int g = blockIdx.x & 7;      // batch group
  const int c = blockIdx.x >> 3;     // col group 0..31
  const int b0 = g << 4;
  const int hcol0 = c << 6;
  const int ocol0 = c << 4;
  const int m16 = lane & 15;
  const int q = lane >> 4;

  // one-time: Wh B-fragments for this wave's 16 h-cols, all K=2048 -> 64 frags in VGPRs
  s16x8 bf_h[64];
  {
    const s16x8* wrow =
        (const s16x8*)(Whb + (size_t)(hcol0 + (w << 4) + m16) * H_DIM + q * 8);
#pragma unroll
    for (int kk = 0; kk < 64; ++kk) bf_h[kk] = wrow[kk * 4];
  }
  // one-time: Wo B-fragments for this wave's K-slice [512w, 512w+512)
  s16x8 bf_o[16];
  {
    const s16x8* orow =
        (const s16x8*)(Wob + (size_t)(ocol0 + m16) * H_DIM + (w << 9) + q * 8);
#pragma unroll
    for (int kk = 0; kk < 16; ++kk) bf_o[kk] = orow[kk * 4];
  }
  const float bh_v = bh[hcol0 + (w << 4) + m16];
  const float bo_v = bo[ocol0 + (tid & 15)];

  int* bar_g = bar + g * 32;  // 128B-padded counter per group

  const int sr = tid >> 4;  // staging row 0..15
  const int sc = tid & 15;  // staging lane-within-row 0..15 (8B units, stride 16)

  for (int i = 0; i <= T_DIM; ++i) {
    // wait until all 32 blocks of the group published s_i (one relaxed add each per step)
    if (i > 0 && tid == 0) {
      const int target = i << 5;
      while (__hip_atomic_load(bar_g, __ATOMIC_RELAXED, __HIP_MEMORY_SCOPE_AGENT) < target) {
        __builtin_amdgcn_s_sleep(1);
      }
    }
    __syncthreads();

    // prefetch this step's embedding-projection values (independent of h_t; L2-warm)
    float ew_pre[4];
    if (i < T_DIM) {
      const int n = hcol0 + (w << 4) + m16;
#pragma unroll
      for (int ii = 0; ii < 4; ++ii) {
        int b = b0 + (q << 2) + ii;
        int xv = x[i * B_DIM + b];
        ew_pre[ii] = EW[(size_t)xv * H_DIM + n];
      }
    }

    // stage s_i[b0..b0+16, :] -> LDS, XOR-swizzled [chunk(16B)][row^(chunk&15)][16B]
    if (i == 0) {
#pragma unroll
      for (int j = 0; j < 32; ++j) *(u64*)(smem + (tid << 8) + (j << 3)) = 0ull;
    } else {
      const u64* hsrc = (const u64*)(hbuf + (size_t)(i & 1) * (B_DIM * H_DIM) +
                                     (size_t)(b0 + sr) * H_DIM);
#pragma unroll
      for (int half = 0; half < 2; ++half) {
        u64 v[16];
#pragma unroll
        for (int j = 0; j < 16; ++j) {
          int u = sc + (((half << 4) + j) << 4);
          v[j] = __hip_atomic_load((u64*)(hsrc + u), __ATOMIC_RELAXED,
                                   __HIP_MEMORY_SCOPE_AGENT);
        }
#pragma unroll
        for (int j = 0; j < 16; ++j) {
          int u = sc + (((half << 4) + j) << 4);
          int c4 = u >> 1, hf = u & 1;
          int rp = sr ^ (c4 & 15);
          *(u64*)(smem + (c4 << 8) + (rp << 4) + (hf << 3)) = v[j];
        }
      }
    }
    __syncthreads();

    f32x4 acc[4], acco[2];
#pragma unroll
    for (int j = 0; j < 4; ++j) acc[j] = (f32x4){0, 0, 0, 0};
    acco[0] = (f32x4){0, 0, 0, 0};
    acco[1] = (f32x4){0, 0, 0, 0};

#pragma unroll
    for (int kk = 0; kk < 64; ++kk) {
      int c4 = (kk << 2) + q;
      s16x8 af = *(const s16x8*)(smem + (c4 << 8) + ((m16 ^ (c4 & 15)) << 4));
      acc[kk & 3] = __builtin_amdgcn_mfma_f32_16x16x32_bf16(af, bf_h[kk], acc[kk & 3], 0, 0, 0);
      int ko = kk - (w << 4);
      if ((unsigned)ko < 16u)  // this wave's o K-slice reuses the same A-frag
        acco[ko & 1] = __builtin_amdgcn_mfma_f32_16x16x32_bf16(af, bf_o[ko], acco[ko & 1], 0, 0, 0);
    }

    if (i < T_DIM) {  // h_{i+1} = tanh(EW[x_i] + acc + bh); publish via device-scope stores
      f32x4 a = (acc[0] + acc[1]) + (acc[2] + acc[3]);
      const int n = hcol0 + (w << 4) + m16;
      unsigned short* hdst = hbuf + (size_t)((i + 1) & 1) * (B_DIM * H_DIM);
#pragma unroll
      for (int ii = 0; ii < 4; ++ii) {
        int m = (q << 2) + ii;
        int b = b0 + m;
        float pre = ew_pre[ii] + bh_v + a[ii];
        float th = tanh_fast(pre);
        unsigned short hb = __builtin_bit_cast(unsigned short, __float2bfloat16(th));
        __hip_atomic_store(hdst + (size_t)b * H_DIM + n, hb, __ATOMIC_RELAXED,
                           __HIP_MEMORY_SCOPE_AGENT);
        if (i == T_DIM - 1)  // final hidden state, f32, appended after out
          out[(size_t)T_DIM * B_DIM * O_DIM + (size_t)b * H_DIM + n] = th;
      }
    }

    // every thread drains its device-scope h stores, then block-barrier, then signal.
    __builtin_amdgcn_s_waitcnt(0);
    __syncthreads();  // also: all A-frag LDS reads done -> o_red may alias

    if (i > 0) {
      f32x4 ao = acco[0] + acco[1];
#pragma unroll
      for (int ii = 0; ii < 4; ++ii)
        o_red[(w << 8) + ((q << 2) + ii) * 16 + m16] = ao[ii];
    }
    if (i < T_DIM && tid == 0) {
      __hip_atomic_fetch_add(bar_g, 1, __ATOMIC_RELAXED, __HIP_MEMORY_SCOPE_AGENT);
    }
    __syncthreads();
    if (i > 0) {  // out[i-1] = sum of 4 wave partials + bo
      float v = o_red[tid] + o_red[256 + tid] + o_red[512 + tid] + o_red[768 + tid] + bo_v;
      int m = tid >> 4, n = tid & 15;
      out[(size_t)(i - 1) * (B_DIM * O_DIM) + (size_t)(b0 + m) * O_DIM + ocol0 + n] = v;
    }
  }
}

extern "C" void kernel_launch(void* const* d_in, const int* in_sizes, int n_in,
                              void* d_out, int out_size, void* d_ws, size_t ws_size,
                              hipStream_t stream) {
  const int* x = (const int*)d_in[0];
  const float* emb = (const float*)d_in[1];
  const float* Wi = (const float*)d_in[2];
  const float* bi = (const float*)d_in[3];
  const float* Wh = (const float*)d_in[4];
  const float* bh = (const float*)d_in[5];
  const float* Wo = (const float*)d_in[6];
  const float* bo = (const float*)d_in[7];
  float* out = (float*)d_out;
  char* ws = (char*)d_ws;

  __hip_bfloat16* Whb = (__hip_bfloat16*)(ws + WS_WHB);
  __hip_bfloat16* Wob = (__hip_bfloat16*)(ws + WS_WOB);
  __hip_bfloat16* embb = (__hip_bfloat16*)(ws + WS_EMBB);
  __hip_bfloat16* Wib = (__hip_bfloat16*)(ws + WS_WIB);
  float* EW = (float*)(ws + WS_EW);
  unsigned short* hbuf = (unsigned short*)(ws + WS_HBUF);
  int* bar = (int*)(ws + WS_BAR);

  // barrier counters also zeroed via device-scope stores in ew_kernel (MALL-authoritative)
  hipMemsetAsync(ws + WS_BAR, 0, 1024, stream);

  cast_bf16_kernel<<<2048, 256, 0, stream>>>(Wh, Whb, 524288);
  cast_bf16_kernel<<<512, 256, 0, stream>>>(Wo, Wob, 131072);
  cast_bf16_kernel<<<128, 256, 0, stream>>>(emb, embb, 32768);
  cast_bf16_kernel<<<512, 256, 0, stream>>>(Wi, Wib, 131072);
  ew_kernel<<<1024, 256, 0, stream>>>(embb, Wib, bi, EW, bar);
  rnn_persistent<<<256, 256, 65536, stream>>>(x, EW, Whb, Wob, bh, bo, hbuf, bar, out);
}